// Round 9
// baseline (613.977 us; speedup 1.0000x reference)
//
#include <hip/hip_runtime.h>
#include <cstdint>
#include <cstddef>

typedef unsigned short u16;
typedef __attribute__((ext_vector_type(8))) short short8;    // 8 bf16 (4 VGPR)
typedef __attribute__((ext_vector_type(16))) float f32x16;   // 32x32 MFMA C/D
typedef __attribute__((ext_vector_type(4))) int i32x4;

constexpr int M  = 8192;
constexpr int Nn = 4096;
constexpr int K1 = 2048;
constexpr int K2 = 4096;
constexpr int K  = K1 + K2;            // 6144
constexpr int BM = 256, BN = 256;
constexpr int NBK = K / 64;            // 96 K-tiles of BK=64
constexpr float LEAK = 0.3f;

__device__ __forceinline__ u16 f2bf(float f) {
  unsigned u = __float_as_uint(f);
  u += 0x7FFFu + ((u >> 16) & 1u);     // RNE
  return (u16)(u >> 16);
}

// ---- blocked cast+concat (unchanged): 64x64 bf16 blocks in k-major slot
// order. Block (g,t) at ((g*NBK)+t)*4096 el; slot s = rb2*256+kc*32+r <->
// row rb2*32+r, col-chunk kc. DMA/frag addressing is base + lane*16B.
template<int C1, int C2>
__global__ void cast_concat_blk(const float* __restrict__ X, const float* __restrict__ S,
                                u16* __restrict__ out)
{
  __shared__ u16 tile[64 * 72];
  const int bid = blockIdx.x;
  const int t   = bid % NBK;
  const int g   = bid / NBK;
  const int tid = threadIdx.x;         // 256
  const int row = tid >> 2;
  const int cs  = (tid & 3) * 16;
  const int gcol = t * 64 + cs;
  const int grow = g * 64 + row;
  const float* src = (gcol < C1) ? (X + (size_t)grow * C1 + gcol)
                                 : (S + (size_t)grow * C2 + (gcol - C1));
  const float4* s4 = (const float4*)src;
  u16* d = tile + row * 72 + cs;
  #pragma unroll
  for (int q = 0; q < 4; ++q) {
    float4 f = s4[q];
    d[q * 4 + 0] = f2bf(f.x); d[q * 4 + 1] = f2bf(f.y);
    d[q * 4 + 2] = f2bf(f.z); d[q * 4 + 3] = f2bf(f.w);
  }
  __syncthreads();
  u16* ob = out + (size_t)bid * 4096;
  #pragma unroll
  for (int h = 0; h < 2; ++h) {
    const int s   = tid + h * 256;
    const int rb2 = s >> 8, kc = (s >> 5) & 7, r = s & 31;
    const u16* p  = tile + (rb2 * 32 + r) * 72 + kc * 8;
    *(i32x4*)(ob + s * 8) = *(const i32x4*)p;
  }
}

__device__ __forceinline__ void gload16(const u16* g, u16* l) {
  __builtin_amdgcn_global_load_lds(
      (const __attribute__((address_space(1))) void*)g,
      (__attribute__((address_space(3))) void*)l, 16, 0, 0);
}

__device__ __forceinline__ float fast_tanh(float x) {
  const float ax = __builtin_fabsf(x);
  const float e  = __builtin_amdgcn_exp2f(ax * 2.8853900817779268f); // 2*log2(e)
  const float r  = 1.0f - 2.0f * __builtin_amdgcn_rcpf(e + 1.0f);
  return __builtin_copysignf(r, x);
}

#define BAR()    __builtin_amdgcn_s_barrier()
#define LGKM0()  asm volatile("s_waitcnt lgkmcnt(0)" ::: "memory")
#define LGKM4()  asm volatile("s_waitcnt lgkmcnt(4)" ::: "memory")
#define VMW4()   asm volatile("s_waitcnt vmcnt(4)" ::: "memory")
#define VMW8()   asm volatile("s_waitcnt vmcnt(8)" ::: "memory")
#define VMW12()  asm volatile("s_waitcnt vmcnt(12)" ::: "memory")
#define SB0()    __builtin_amdgcn_sched_barrier(0)

// ROUND-9: A operand bypasses LDS entirely. All prior schedules (r1/r2/r6)
// pinned at MfmaUtil ~52% with IDENTICAL LDS traffic (~512 kB/iter through
// one 55-85 B/cyc pipe) -> LDS-pipe-bound. Blocked A means each wave's
// frag set for (mg, ktile) is global_load_dwordx4 at gbase + mtl*4096B +
// ks*1024B + lane*16B -- same addressing as the old ds_read_b128, loaded
// straight to registers. LDS now holds only B (B0@el0, B1@el16384; 64 KiB).
// LDS traffic/iter: 512 kB -> 192 kB (<< MFMA 4.13 kcyc) -> MFMA-bound.
// Compiler auto-inserts exact vmcnt waits for register A-loads; manual vm
// fences only for DMA-staged B:
//   vm stream/iter (order pinned by SB0): ph2:A8 | ph3:A8,S4 | ph6:A8 |
//   ph7:A8,S4 = 32. VMW12@ph3 retires [prev-ph7 S4 (B(T+1), read ph4/ph5)
//   + ph2 A8]; VMW12@ph7 retires [ph3 S4 (B(T+2), read ph8/next-ph1) +
//   ph6 A8]. Reads of staged B are >=1 barrier after the fence. WAR on
//   B0/B1: last reads lgkm-retired >=1 phase + barrier before each stgB.
// Frag-reg overwrite hazards checked: each set's gld/dsB issue is >=1
// barrier after that set's last MFMA use.
__global__ __launch_bounds__(512, 2) void gemm_fused(
    const u16* __restrict__ A,      // blocked [M/64][96] 64x64 k-major blocks
    const u16* __restrict__ W,      // blocked [Nn/64][96]
    const float* __restrict__ prev, // [M][N] fp32
    float* __restrict__ out)        // [M][N] fp32
{
  __shared__ u16 lds[32768];        // 64 KiB: B0 @ el 0, B1 @ el 16384

  const int tid  = threadIdx.x;
  const int lane = tid & 63;
  const int wid  = tid >> 6;
  const int wr   = wid >> 2;        // 0..1 -> 128-row half of C
  const int wc   = wid & 3;         // 0..3 -> 64-col quarter of C

  // XCD-aware bijective swizzle (512 % 8 == 0)
  const int cpx = gridDim.x >> 3;
  const int wg  = ((int)blockIdx.x & 7) * cpx + ((int)blockIdx.x >> 3);
  const int bn  = wg & 15;          // Nn/BN = 16
  const int bm  = wg >> 4;          // M/BM  = 32

  constexpr size_t BLK = 4096;      // elements per 64x64 block
  u16* ldsw = lds + wid * 512;      // wave-uniform 1KB LDS chunk

  auto stgB = [&](int t, int bufel) {    // full 256x64 B tile, 4 gload16
    #pragma unroll
    for (int r = 0; r < 4; ++r)
      gload16(W + ((size_t)(4 * bn + r) * NBK + t) * BLK + tid * 8,
              ldsw + bufel + r * 4096);
  };

  short8 afE[2][4], afO[2][4];      // A frags (registers, from global)
  short8 bfE[4],    bfO[4];         // B frags (from LDS)
  f32x16 acc[4][2];
  #pragma unroll
  for (int mt = 0; mt < 4; ++mt)
    #pragma unroll
    for (int ng = 0; ng < 2; ++ng) acc[mt][ng] = (f32x16)0.f;

  auto gldA = [&](short8 (&Av)[2][4], int mg, int t) {   // 8 global dwordx4
    const u16* g = A + ((size_t)(4 * bm + wr * 2 + mg) * NBK + t) * BLK + lane * 8;
    #pragma unroll
    for (int mtl = 0; mtl < 2; ++mtl)
      #pragma unroll
      for (int ks = 0; ks < 4; ++ks)
        Av[mtl][ks] = *(const short8*)(g + mtl * 2048 + ks * 512);
  };
  auto dsB = [&](short8 (&Bv)[4], int ng, int bb) {      // 4 ds_read_b128
    const int rb = wc * 2 + ng;
    #pragma unroll
    for (int ks = 0; ks < 4; ++ks)
      Bv[ks] = *(const short8*)(lds + bb + rb * 2048 + ks * 512 + lane * 8);
  };
  auto MM = [&](short8 (&Av)[2][4], short8 (&Bv)[4], int mg, int ng) {  // 8 MFMA
    __builtin_amdgcn_s_setprio(1);
    #pragma unroll
    for (int ks = 0; ks < 4; ++ks)
      #pragma unroll
      for (int mtl = 0; mtl < 2; ++mtl)
        acc[mg * 2 + mtl][ng] = __builtin_amdgcn_mfma_f32_32x32x16_bf16(
            Av[mtl][ks], Bv[ks], acc[mg * 2 + mtl][ng], 0, 0, 0);
    __builtin_amdgcn_s_setprio(0);
  };

  // ---- prologue: afE(0) regs; B(0)->B0, B(1)->B1; wait A8+B0 landed
  gldA(afE, 0, 0);
  SB0();
  stgB(0, 0);
  stgB(1, 16384);
  VMW4();                            // retire A8 + B0's S4; B1's S4 in flight
  BAR();
  dsB(bfE, 0, 0);                    // tile0 ng0

  #pragma unroll 1
  for (int i = 0; i < 47; ++i) {     // tiles T=2i (B0), T+1 (B1)
    const int T = 2 * i;
    // ph1
    dsB(bfO, 1, 0);
    LGKM4(); SB0(); MM(afE, bfE, 0, 0); BAR();
    // ph2
    gldA(afO, 1, T);
    LGKM0(); SB0(); MM(afE, bfO, 0, 1); BAR();
    // ph3: B0 free (bfO retired ph2 + bar) -> stage B(T+2)
    gldA(afE, 0, T + 1);
    SB0();
    stgB(T + 2, 0);
    VMW12(); SB0(); MM(afO, bfE, 1, 0); BAR();   // retires prev-S4 + ph2 A8
    // ph4
    dsB(bfE, 0, 16384);
    SB0(); MM(afO, bfO, 1, 1); BAR();
    // ph5
    dsB(bfO, 1, 16384);
    LGKM4(); SB0(); MM(afE, bfE, 0, 0); BAR();
    // ph6
    gldA(afO, 1, T + 1);
    LGKM0(); SB0(); MM(afE, bfO, 0, 1); BAR();
    // ph7: B1 free -> stage B(T+3)
    gldA(afE, 0, T + 2);
    SB0();
    stgB(T + 3, 16384);
    VMW12(); SB0(); MM(afO, bfE, 1, 0); BAR();   // retires ph3 S4 + ph6 A8
    // ph8
    dsB(bfE, 0, 0);
    SB0(); MM(afO, bfO, 1, 1); BAR();
  }

  // ---- tail: tiles 94 (B0), 95 (B1); afE(94) already in flight, B95 staged
  dsB(bfO, 1, 0);
  LGKM4(); SB0(); MM(afE, bfE, 0, 0); BAR();
  gldA(afO, 1, 94);
  LGKM0(); SB0(); MM(afE, bfO, 0, 1); BAR();
  gldA(afE, 0, 95);
  VMW8();                            // retire B95's S4 + afO burst
  SB0(); MM(afO, bfE, 1, 0); BAR();
  dsB(bfE, 0, 16384);
  SB0(); MM(afO, bfO, 1, 1); BAR();
  dsB(bfO, 1, 16384);
  LGKM4(); SB0(); MM(afE, bfE, 0, 0); BAR();
  gldA(afO, 1, 95);
  LGKM0(); SB0(); MM(afE, bfO, 0, 1); BAR();
  SB0(); MM(afO, bfE, 1, 0);
  MM(afO, bfO, 1, 1);

  // ---- epilogue: 32x32 C/D: col=lane&31, row=(j&3)+8*(j>>2)+4*(lane>>5)
  const int l31 = lane & 31, l5 = lane >> 5;
  const int crow0 = bm * BM + wr * 128 + l5 * 4;
  const int ccol0 = bn * BN + wc * 64 + l31;
  #pragma unroll
  for (int mt = 0; mt < 4; ++mt)
    #pragma unroll
    for (int ng = 0; ng < 2; ++ng)
      #pragma unroll
      for (int j = 0; j < 16; ++j) {
        const int row = crow0 + mt * 32 + (j & 3) + 8 * (j >> 2);
        const size_t off = (size_t)row * Nn + ccol0 + ng * 32;
        out[off] = (1.0f - LEAK) * prev[off] + LEAK * fast_tanh(acc[mt][ng][j]);
      }
}

extern "C" void kernel_launch(void* const* d_in, const int* in_sizes, int n_in,
                              void* d_out, int out_size, void* d_ws, size_t ws_size,
                              hipStream_t stream) {
  const float* inputs = (const float*)d_in[0];  // [8192][2048]
  const float* prev   = (const float*)d_in[1];  // [8192][4096]
  const float* w_in   = (const float*)d_in[2];  // [4096][2048]
  const float* w_res  = (const float*)d_in[3];  // [4096][4096]
  float* out = (float*)d_out;                   // [8192][4096]

  u16* Acat = (u16*)d_ws;                        // blocked [M/64][96] 4096-el blocks
  u16* Wcat = Acat + (size_t)M * K;              // blocked [Nn/64][96]

  cast_concat_blk<K1, K2><<<(M / 64) * NBK, 256, 0, stream>>>(inputs, prev, Acat);
  cast_concat_blk<K1, K2><<<(Nn / 64) * NBK, 256, 0, stream>>>(w_in, w_res, Wcat);

  gemm_fused<<<(M / BM) * (Nn / BN), 512, 0, stream>>>(Acat, Wcat, prev, out);
}

// Round 10
// 452.841 us; speedup vs baseline: 1.3558x; 1.3558x over previous
//
#include <hip/hip_runtime.h>
#include <cstdint>
#include <cstddef>

typedef unsigned short u16;
typedef __attribute__((ext_vector_type(8))) short short8;    // 8 bf16 (4 VGPR)
typedef __attribute__((ext_vector_type(16))) float f32x16;   // 32x32 MFMA C/D
typedef __attribute__((ext_vector_type(4))) float f32x4;     // true vector 16B
typedef __attribute__((ext_vector_type(4))) int i32x4;

constexpr int M  = 8192;
constexpr int Nn = 4096;
constexpr int K1 = 2048;
constexpr int K2 = 4096;
constexpr int K  = K1 + K2;            // 6144
constexpr int BM = 256, BN = 256;
constexpr int NBK = K / 64;            // 96 K-tiles of BK=64
constexpr float LEAK = 0.3f;

__device__ __forceinline__ u16 f2bf(float f) {
  unsigned u = __float_as_uint(f);
  u += 0x7FFFu + ((u >> 16) & 1u);     // RNE
  return (u16)(u >> 16);
}

// ---- blocked cast+concat (unchanged, proven): 64x64 bf16 blocks in k-major
// slot order. Block (g,t) at ((g*NBK)+t)*4096 el; slot s = rb2*256+kc*32+r.
template<int C1, int C2>
__global__ void cast_concat_blk(const float* __restrict__ X, const float* __restrict__ S,
                                u16* __restrict__ out)
{
  __shared__ u16 tile[64 * 72];
  const int bid = blockIdx.x;
  const int t   = bid % NBK;
  const int g   = bid / NBK;
  const int tid = threadIdx.x;         // 256
  const int row = tid >> 2;
  const int cs  = (tid & 3) * 16;
  const int gcol = t * 64 + cs;
  const int grow = g * 64 + row;
  const float* src = (gcol < C1) ? (X + (size_t)grow * C1 + gcol)
                                 : (S + (size_t)grow * C2 + (gcol - C1));
  const float4* s4 = (const float4*)src;
  u16* d = tile + row * 72 + cs;
  #pragma unroll
  for (int q = 0; q < 4; ++q) {
    float4 f = s4[q];
    d[q * 4 + 0] = f2bf(f.x); d[q * 4 + 1] = f2bf(f.y);
    d[q * 4 + 2] = f2bf(f.z); d[q * 4 + 3] = f2bf(f.w);
  }
  __syncthreads();
  u16* ob = out + (size_t)bid * 4096;
  #pragma unroll
  for (int h = 0; h < 2; ++h) {
    const int s   = tid + h * 256;
    const int rb2 = s >> 8, kc = (s >> 5) & 7, r = s & 31;
    const u16* p  = tile + (rb2 * 32 + r) * 72 + kc * 8;
    *(i32x4*)(ob + s * 8) = *(const i32x4*)p;
  }
}

__device__ __forceinline__ void gload16(const u16* g, u16* l) {
  __builtin_amdgcn_global_load_lds(
      (const __attribute__((address_space(1))) void*)g,
      (__attribute__((address_space(3))) void*)l, 16, 0, 0);
}

__device__ __forceinline__ float fast_tanh(float x) {
  const float ax = __builtin_fabsf(x);
  const float e  = __builtin_amdgcn_exp2f(ax * 2.8853900817779268f); // 2*log2(e)
  const float r  = 1.0f - 2.0f * __builtin_amdgcn_rcpf(e + 1.0f);
  return __builtin_copysignf(r, x);
}

#define BAR()    __builtin_amdgcn_s_barrier()
#define LGKM0()  asm volatile("s_waitcnt lgkmcnt(0)" ::: "memory")
#define LGKM4()  asm volatile("s_waitcnt lgkmcnt(4)" ::: "memory")
#define LGKM8()  asm volatile("s_waitcnt lgkmcnt(8)" ::: "memory")
#define VMW4()   asm volatile("s_waitcnt vmcnt(4)" ::: "memory")
#define VMW0()   asm volatile("s_waitcnt vmcnt(0)" ::: "memory")
#define SB0()    __builtin_amdgcn_sched_barrier(0)

// ROUND-10: r6/r8 dataflow (32x32x16, k-major blocked LDS, 0 conflicts) with
// HALF the barriers: 4/iter, after ph2/ph4/ph6/ph8 only. Windows W1={1,2},
// W2={3,4}, W3={5,6}, W4={7,8}. Stage map moved so every cross-wave WAR has
// a barrier between the reader's lgkm-retirement and the stage:
//   ph1: A1<-T+1 (A1 old reads: ph6 afO, retired ph7-LGKM8 in W4; bar8)
//   ph3: B0<-T+2 (B0 old: ph1 bfO, retired ph2-LGKM8 in W1; bar2)
//   ph5: A0<-T+2 (A0 old: ph2 afO, retired ph3-LGKM8 in W2; bar4)
//   ph7: B1<-T+3 (B1 old: ph4/ph5, retired ph5-LGKM4/ph6-LGKM8 in W3; bar6)
// RAW fences (both already in r6): VMW0@ph2-end retires {prev-ph7 B1-stage
// (read ph4/5), ph1 A1-stage (read ph3/6)} with bar2 before the reads;
// VMW0@ph6-end retires {ph3 B0-stage (read ph8/next-ph1), ph5 A0-stage
// (read ph7/next-ph2)} with bar6 before the reads.
// LGKM counts re-traced for the new issue stream (4/8/8/4/4/8/8/4 reads,
// stages affect vmcnt only): ph1-LGKM4 retires prev ph7+ph8 (12) = its MM
// operands; ph3-LGKM8 retires ph2's 8; ph5-LGKM4 retires ph3+ph4 (12);
// ph6-LGKM8 retires ph5; ph7-LGKM8 retires ph6; ph4/ph8 need no wait
// (operands retired by ph3/ph7 waits). All verified operand-by-operand.
__global__ __launch_bounds__(512, 2) void gemm_fused(
    const u16* __restrict__ A,      // blocked [M/64][96] 64x64 k-major blocks
    const u16* __restrict__ W,      // blocked [Nn/64][96]
    const float* __restrict__ prev, // [M][N] fp32
    float* __restrict__ out)        // [M][N] fp32
{
  // loop: A0@0 A1@16384 B0@32768 B1@49152 (u16 elements, 128 KiB);
  // epilogue: 8 x 17408 B private slices = 139264 B
  __shared__ u16 lds[69632];

  const int tid  = threadIdx.x;
  const int lane = tid & 63;
  const int wid  = tid >> 6;
  const int wr   = wid >> 2;        // 0..1 -> 128-row half of C
  const int wc   = wid & 3;         // 0..3 -> 64-col quarter of C

  // XCD-aware bijective swizzle (512 % 8 == 0)
  const int cpx = gridDim.x >> 3;
  const int wg  = ((int)blockIdx.x & 7) * cpx + ((int)blockIdx.x >> 3);
  const int bn  = wg & 15;          // Nn/BN = 16
  const int bm  = wg >> 4;          // M/BM  = 32

  constexpr size_t BLK = 4096;
  constexpr size_t RG  = (size_t)NBK * BLK;       // 393216
  const u16* pA = A + (size_t)(4 * bm) * RG + tid * 8;
  const u16* pW = W + (size_t)(4 * bn) * RG + tid * 8;
  u16* ldsw = lds + wid * 512;      // wave-uniform slot base (1KB/wave)

  auto stgT = [&](const u16* p, int t, int bufel) {  // full 256x64 tile, 4 loads
    #pragma unroll
    for (int r = 0; r < 4; ++r)
      gload16(p + (size_t)r * RG + (size_t)t * BLK, ldsw + bufel + r * 4096);
  };

  short8 afE[2][4], afO[2][4];      // A frags: 2 mt-locals x 4 ks
  short8 bfE[4],    bfO[4];         // B frags: 4 ks
  f32x16 acc[4][2];
  #pragma unroll
  for (int mt = 0; mt < 4; ++mt)
    #pragma unroll
    for (int ng = 0; ng < 2; ++ng) acc[mt][ng] = (f32x16)0.f;

  auto dsA = [&](short8 (&Av)[2][4], int mg, int ab) {   // 8 ds_read_b128
    #pragma unroll
    for (int mtl = 0; mtl < 2; ++mtl) {
      const int rb = wr * 4 + mg * 2 + mtl;
      #pragma unroll
      for (int ks = 0; ks < 4; ++ks)
        Av[mtl][ks] = *(const short8*)(lds + ab + rb * 2048 + ks * 512 + lane * 8);
    }
  };
  auto dsB = [&](short8 (&Bv)[4], int ng, int bb) {      // 4 ds_read_b128
    const int rb = wc * 2 + ng;
    #pragma unroll
    for (int ks = 0; ks < 4; ++ks)
      Bv[ks] = *(const short8*)(lds + bb + rb * 2048 + ks * 512 + lane * 8);
  };
  auto MM = [&](short8 (&Av)[2][4], short8 (&Bv)[4], int mg, int ng) {  // 8 MFMA
    __builtin_amdgcn_s_setprio(1);
    #pragma unroll
    for (int ks = 0; ks < 4; ++ks)
      #pragma unroll
      for (int mtl = 0; mtl < 2; ++mtl)
        acc[mg * 2 + mtl][ng] = __builtin_amdgcn_mfma_f32_32x32x16_bf16(
            Av[mtl][ks], Bv[ks], acc[mg * 2 + mtl][ng], 0, 0, 0);
    __builtin_amdgcn_s_setprio(0);
  };

  // ---- prologue: B(0)->B0, A(0)->A0, B(1)->B1 (12 loads; A(1) staged at
  // iter0-ph1). VMW4 retires B0+A0; B1 fenced by ph2's VMW0 before ph4 read.
  stgT(pW, 0, 32768);
  stgT(pA, 0, 0);
  stgT(pW, 1, 49152);
  VMW4();
  BAR();
  dsA(afE, 0, 0);                   // tile0 mg0
  dsB(bfE, 0, 32768);               // tile0 ng0

  #pragma unroll 1
  for (int i = 0; i < 47; ++i) {    // tiles T=2i (A0/B0), T+1 (A1/B1)
    const int T = 2 * i;
    // ph1: stage A1<-T+1
    dsB(bfO, 1, 32768);
    stgT(pA, T + 1, 16384);
    LGKM4(); SB0(); MM(afE, bfE, 0, 0);
    // ph2
    dsA(afO, 1, 0);
    LGKM8(); SB0(); MM(afE, bfO, 0, 1); VMW0(); BAR();
    // ph3: stage B0<-T+2
    dsA(afE, 0, 16384);             // A1 tile T+1 mg0
    stgT(pW, T + 2, 32768);
    LGKM8(); SB0(); MM(afO, bfE, 1, 0);
    // ph4
    dsB(bfE, 0, 49152);             // B1 tile T+1 ng0
    SB0(); MM(afO, bfO, 1, 1); BAR();
    // ph5: stage A0<-T+2
    dsB(bfO, 1, 49152);
    stgT(pA, T + 2, 0);
    LGKM4(); SB0(); MM(afE, bfE, 0, 0);
    // ph6
    dsA(afO, 1, 16384);             // A1 tile T+1 mg1
    LGKM8(); SB0(); MM(afE, bfO, 0, 1); VMW0(); BAR();
    // ph7: stage B1<-T+3
    dsA(afE, 0, 0);                 // A0 tile T+2 mg0 (prefetch)
    stgT(pW, T + 3, 49152);
    LGKM8(); SB0(); MM(afO, bfE, 1, 0);
    // ph8
    dsB(bfE, 0, 32768);             // B0 tile T+2 ng0 (prefetch)
    SB0(); MM(afO, bfO, 1, 1); BAR();
  }

  // ---- tail: T=94 (A0/B0), 95 (A1/B1); stage only A1<-95 at tp1
  dsB(bfO, 1, 32768);
  stgT(pA, 95, 16384);
  LGKM4(); SB0(); MM(afE, bfE, 0, 0);
  dsA(afO, 1, 0);
  LGKM8(); SB0(); MM(afE, bfO, 0, 1); VMW0(); BAR();
  dsA(afE, 0, 16384);               // A1 tile95 mg0
  LGKM8(); SB0(); MM(afO, bfE, 1, 0);
  dsB(bfE, 0, 49152);               // B1 tile95 ng0 (staged loop-ph7; VMW0 ✓)
  SB0(); MM(afO, bfO, 1, 1); BAR();
  dsB(bfO, 1, 49152);
  LGKM4(); SB0(); MM(afE, bfE, 0, 0);
  dsA(afO, 1, 16384);
  LGKM8(); SB0(); MM(afE, bfO, 0, 1);
  LGKM0(); SB0(); MM(afO, bfE, 1, 0);
  MM(afO, bfO, 1, 1);

  // ---- epilogue (r8, passed): per-wave LDS transpose + f32x4 nt streams.
  BAR();
  float* T = (float*)((char*)lds + wid * 17408);   // 64 rows x 68 floats
  const int l31 = lane & 31, l5 = lane >> 5;
  const int c16 = lane & 15, g4 = lane >> 4;
  #pragma unroll
  for (int ch = 0; ch < 2; ++ch) {
    #pragma unroll
    for (int mtl = 0; mtl < 2; ++mtl)
      #pragma unroll
      for (int ng = 0; ng < 2; ++ng)
        #pragma unroll
        for (int j = 0; j < 16; ++j) {
          const int rowl = mtl * 32 + (j & 3) + 8 * (j >> 2) + l5 * 4;
          T[rowl * 68 + ng * 32 + l31] = acc[ch * 2 + mtl][ng][j];
        }
    LGKM0();
    const int grow0 = bm * BM + wr * 128 + ch * 64;
    const size_t gcb = (size_t)(bn * BN + wc * 64 + c16 * 4);
    #pragma unroll 4
    for (int q = 0; q < 16; ++q) {
      const int rowl = q * 4 + g4;
      const f32x4 t = *(const f32x4*)&T[rowl * 68 + c16 * 4];
      const size_t off = (size_t)(grow0 + rowl) * Nn + gcb;
      const f32x4 p = __builtin_nontemporal_load((const f32x4*)(prev + off));
      f32x4 o;
      o.x = (1.0f - LEAK) * p.x + LEAK * fast_tanh(t.x);
      o.y = (1.0f - LEAK) * p.y + LEAK * fast_tanh(t.y);
      o.z = (1.0f - LEAK) * p.z + LEAK * fast_tanh(t.z);
      o.w = (1.0f - LEAK) * p.w + LEAK * fast_tanh(t.w);
      __builtin_nontemporal_store(o, (f32x4*)(out + off));
    }
  }
}

extern "C" void kernel_launch(void* const* d_in, const int* in_sizes, int n_in,
                              void* d_out, int out_size, void* d_ws, size_t ws_size,
                              hipStream_t stream) {
  const float* inputs = (const float*)d_in[0];  // [8192][2048]
  const float* prev   = (const float*)d_in[1];  // [8192][4096]
  const float* w_in   = (const float*)d_in[2];  // [4096][2048]
  const float* w_res  = (const float*)d_in[3];  // [4096][4096]
  float* out = (float*)d_out;                   // [8192][4096]

  u16* Acat = (u16*)d_ws;                        // blocked [M/64][96] 4096-el blocks
  u16* Wcat = Acat + (size_t)M * K;              // blocked [Nn/64][96]

  cast_concat_blk<K1, K2><<<(M / 64) * NBK, 256, 0, stream>>>(inputs, prev, Acat);
  cast_concat_blk<K1, K2><<<(Nn / 64) * NBK, 256, 0, stream>>>(w_in, w_res, Wcat);

  gemm_fused<<<(M / BM) * (Nn / BN), 512, 0, stream>>>(Acat, Wcat, prev, out);
}